// Round 1
// baseline (794.760 us; speedup 1.0000x reference)
//
#include <hip/hip_runtime.h>
#include <hip/hip_bf16.h>
#include <cstddef>

#define Bb 8
#define Tt 512
#define NM 128
#define DM 512
#define DI 1024
#define DS 32
#define DR 32
#define DC 4
#define NC 100
#define BT (Bb*Tt)   // 4096

__device__ __forceinline__ float softplus_f(float x) {
    return fmaxf(x, 0.f) + log1pf(expf(-fabsf(x)));
}
__device__ __forceinline__ float silu_f(float x) {
    return x / (1.f + expf(-x));
}

// ---------------- generic 64x64 tiled fp32 GEMM: C = epi(A@B) -----------------
// A: (M,K) row-major with row stride lda; B: (K,N) row-major stride N.
// EPI: 0 none, 1 +bias[n], 2 softplus(+bias[n]), 3 +add[m*N+n]
template<int EPI>
__global__ __launch_bounds__(256) void gemm64(
    const float* __restrict__ A, int lda,
    const float* __restrict__ B,
    const float* __restrict__ bias,
    const float* __restrict__ add,
    float* __restrict__ C,
    int M, int N, int K)
{
    __shared__ float As[16][68];   // [k][m], pad 68 keeps store conflicts 2-way (free)
    __shared__ float Bs[16][64];   // [k][n]
    const int tid = threadIdx.x;
    const int bm = blockIdx.y * 64;
    const int bn = blockIdx.x * 64;
    const int tx = tid & 15;          // n quad
    const int ty = tid >> 4;          // m quad
    const int la_m = tid >> 2;        // 0..63
    const int la_k = (tid & 3) << 2;  // 0,4,8,12
    const int lb_k = tid >> 4;        // 0..15
    const int lb_n = (tid & 15) << 2; // 0..60

    float acc[4][4] = {};
    for (int k0 = 0; k0 < K; k0 += 16) {
        float4 av = *(const float4*)(A + (size_t)(bm + la_m) * lda + k0 + la_k);
        As[la_k + 0][la_m] = av.x;
        As[la_k + 1][la_m] = av.y;
        As[la_k + 2][la_m] = av.z;
        As[la_k + 3][la_m] = av.w;
        const int gn = bn + lb_n;
        const float* bp = B + (size_t)(k0 + lb_k) * N + gn;
        float4 bv;
        if (gn + 3 < N) {
            bv = *(const float4*)bp;
        } else {
            bv.x = (gn + 0 < N) ? bp[0] : 0.f;
            bv.y = (gn + 1 < N) ? bp[1] : 0.f;
            bv.z = (gn + 2 < N) ? bp[2] : 0.f;
            bv.w = (gn + 3 < N) ? bp[3] : 0.f;
        }
        *(float4*)&Bs[lb_k][lb_n] = bv;
        __syncthreads();
        #pragma unroll
        for (int k = 0; k < 16; ++k) {
            float4 a = *(const float4*)&As[k][ty << 2];
            float4 b = *(const float4*)&Bs[k][tx << 2];
            float ar[4] = {a.x, a.y, a.z, a.w};
            float br[4] = {b.x, b.y, b.z, b.w};
            #pragma unroll
            for (int i = 0; i < 4; ++i)
                #pragma unroll
                for (int j = 0; j < 4; ++j)
                    acc[i][j] = fmaf(ar[i], br[j], acc[i][j]);
        }
        __syncthreads();
    }
    #pragma unroll
    for (int i = 0; i < 4; ++i) {
        const int gm = bm + (ty << 2) + i;
        #pragma unroll
        for (int j = 0; j < 4; ++j) {
            const int gn = bn + (tx << 2) + j;
            if (gn < N) {
                float v = acc[i][j];
                if (EPI == 1) v += bias[gn];
                else if (EPI == 2) v = softplus_f(v + bias[gn]);
                else if (EPI == 3) v += add[(size_t)gm * N + gn];
                C[(size_t)gm * N + gn] = v;
            }
        }
    }
}

// ---------------- RMSNorm over DM=512, one block per row ----------------------
__global__ __launch_bounds__(256) void rms_kernel(
    const float* __restrict__ h0, const float* __restrict__ w, float* __restrict__ xn)
{
    const int row = blockIdx.x;
    const float* p = h0 + (size_t)row * DM;
    const int tid = threadIdx.x;
    float v0 = p[tid], v1 = p[tid + 256];
    float ss = v0 * v0 + v1 * v1;
    #pragma unroll
    for (int m = 32; m; m >>= 1) ss += __shfl_xor(ss, m);
    __shared__ float wsum[4];
    if ((tid & 63) == 0) wsum[tid >> 6] = ss;
    __syncthreads();
    const float tot = wsum[0] + wsum[1] + wsum[2] + wsum[3];
    const float scale = rsqrtf(tot * (1.0f / DM) + 1e-5f);
    xn[(size_t)row * DM + tid]       = v0 * scale * w[tid];
    xn[(size_t)row * DM + tid + 256] = v1 * scale * w[tid + 256];
}

// -------- causal depthwise conv (DC=4) + SiLU; input = xr[:, 0:DI] ------------
__global__ __launch_bounds__(256) void conv_silu_kernel(
    const float* __restrict__ xr, const float* __restrict__ cw,
    const float* __restrict__ cb, float* __restrict__ xp)
{
    const int idx = blockIdx.x * 256 + threadIdx.x;  // over BT*DI
    const int di = idx & (DI - 1);
    const int bt = idx >> 10;
    const int t = bt & (Tt - 1);
    float acc = cb[di];
    #pragma unroll
    for (int j = 0; j < DC; ++j) {
        const int tt = t - (DC - 1) + j;
        if (tt >= 0)
            acc = fmaf(cw[di * DC + j], xr[(size_t)(bt - (DC - 1) + j) * (2 * DI) + di], acc);
    }
    xp[idx] = silu_f(acc);
}

// ---------------- selective scan: lane s of 32 per channel (b,di) -------------
// y_out[bt,di] = (sum_s h_s C_s + u*D[di]) * silu(res)
__global__ __launch_bounds__(256) void scan_kernel(
    const float* __restrict__ delta,  // (BT, DI)
    const float* __restrict__ xdbl,   // (BT, 96): [dt(32) | B(32) | C(32)]
    const float* __restrict__ xp,     // (BT, DI)  u
    const float* __restrict__ xr,     // (BT, 2*DI)  res = [:, DI:]
    const float* __restrict__ A_log,  // (DI, DS)
    const float* __restrict__ Dvec,   // (DI)
    float* __restrict__ y)            // (BT, DI)
{
    const int g = threadIdx.x >> 5;   // group in block: 0..7
    const int s = threadIdx.x & 31;
    const int b = blockIdx.x >> 7;            // DI/8 = 128 blocks per batch
    const int di = ((blockIdx.x & 127) << 3) + g;
    const float Ads = -expf(A_log[di * DS + s]);
    const float Dv = Dvec[di];
    const float* dp = delta + (size_t)b * Tt * DI + di;
    const float* up = xp + (size_t)b * Tt * DI + di;
    const float* rp = xr + (size_t)b * Tt * (2 * DI) + DI + di;
    const float* xd = xdbl + (size_t)b * Tt * 96;
    float* yp = y + (size_t)b * Tt * DI + di;
    float h = 0.f;
    for (int t = 0; t < Tt; ++t) {
        const float dt = dp[(size_t)t * DI];
        const float u  = up[(size_t)t * DI];
        const float Btv = xd[t * 96 + DR + s];
        const float Ctv = xd[t * 96 + DR + DS + s];
        const float dA = expf(dt * Ads);
        h = fmaf(dA, h, dt * u * Btv);
        float ps = h * Ctv;
        ps += __shfl_xor(ps, 16);
        ps += __shfl_xor(ps, 8);
        ps += __shfl_xor(ps, 4);
        ps += __shfl_xor(ps, 2);
        ps += __shfl_xor(ps, 1);
        if (s == 0) {
            const float res = rp[(size_t)t * (2 * DI)];
            yp[(size_t)t * DI] = (ps + u * Dv) * silu_f(res);
        }
    }
}

// ---------------- mean-pool over DM, one wave per row -------------------------
__global__ __launch_bounds__(256) void pool_kernel(
    const float* __restrict__ enc, float* __restrict__ pooled)
{
    const int row = blockIdx.x * 4 + (threadIdx.x >> 6);
    const int lane = threadIdx.x & 63;
    const float* p = enc + (size_t)row * DM;
    float sacc = 0.f;
    #pragma unroll
    for (int i = 0; i < DM / 64; ++i) sacc += p[lane + 64 * i];
    #pragma unroll
    for (int m = 32; m; m >>= 1) sacc += __shfl_xor(sacc, m);
    if (lane == 0) pooled[row] = sacc * (1.0f / DM);
}

// ---------------- classifier: out[b,c] = pooled[b,:] @ w_cls + b_cls ----------
__global__ __launch_bounds__(256) void cls_kernel(
    const float* __restrict__ pooled, const float* __restrict__ w_cls,
    const float* __restrict__ b_cls, float* __restrict__ out)
{
    const int idx = blockIdx.x * 256 + threadIdx.x;
    if (idx >= Bb * NC) return;
    const int b = idx / NC, c = idx % NC;
    float acc = b_cls[c];
    for (int t = 0; t < DM; ++t)
        acc = fmaf(pooled[b * DM + t], w_cls[t * NC + c], acc);
    out[idx] = acc;
}

extern "C" void kernel_launch(void* const* d_in, const int* in_sizes, int n_in,
                              void* d_out, int out_size, void* d_ws, size_t ws_size,
                              hipStream_t stream) {
    const float* x      = (const float*)d_in[0];
    const float* w_proj = (const float*)d_in[1];
    const float* b_proj = (const float*)d_in[2];
    const float* rms_w  = (const float*)d_in[3];
    const float* w_in   = (const float*)d_in[4];
    const float* conv_w = (const float*)d_in[5];
    const float* conv_b = (const float*)d_in[6];
    const float* w_xprj = (const float*)d_in[7];
    const float* w_dt   = (const float*)d_in[8];
    const float* b_dt   = (const float*)d_in[9];
    const float* A_log  = (const float*)d_in[10];
    const float* Dvec   = (const float*)d_in[11];
    const float* w_out  = (const float*)d_in[12];
    const float* w_cls  = (const float*)d_in[13];
    const float* b_cls  = (const float*)d_in[14];
    float* out = (float*)d_out;

    float* ws = (float*)d_ws;
    float* h0     = ws;                          // BT*DM
    float* xn     = h0 + (size_t)BT * DM;        // BT*DM (reused as enc)
    float* xr     = xn + (size_t)BT * DM;        // BT*2DI
    float* xp     = xr + (size_t)BT * 2 * DI;    // BT*DI
    float* xdbl   = xp + (size_t)BT * DI;        // BT*96
    float* delta  = xdbl + (size_t)BT * 96;      // BT*DI
    float* yb     = delta + (size_t)BT * DI;     // BT*DI
    float* pooled = yb + (size_t)BT * DI;        // BT
    float* enc    = xn;                          // alias: xn dead after gemm2

    // 1) h0 = x @ w_proj + b_proj        (4096,128)@(128,512)
    gemm64<1><<<dim3(DM / 64, BT / 64), 256, 0, stream>>>(
        x, NM, w_proj, b_proj, nullptr, h0, BT, DM, NM);
    // 2) xn = rmsnorm(h0) * rms_w
    rms_kernel<<<BT, 256, 0, stream>>>(h0, rms_w, xn);
    // 3) xr = xn @ w_in                  (4096,512)@(512,2048)
    gemm64<0><<<dim3(2 * DI / 64, BT / 64), 256, 0, stream>>>(
        xn, DM, w_in, nullptr, nullptr, xr, BT, 2 * DI, DM);
    // 4) xp = silu(causal_dwconv(xr[:, :DI]))
    conv_silu_kernel<<<BT * DI / 256, 256, 0, stream>>>(xr, conv_w, conv_b, xp);
    // 5) xdbl = xp @ w_xproj             (4096,1024)@(1024,96)
    gemm64<0><<<dim3((96 + 63) / 64, BT / 64), 256, 0, stream>>>(
        xp, DI, w_xprj, nullptr, nullptr, xdbl, BT, 96, DI);
    // 6) delta = softplus(dt @ w_dt + b_dt)   (4096,32)@(32,1024), lda=96
    gemm64<2><<<dim3(DI / 64, BT / 64), 256, 0, stream>>>(
        xdbl, 96, w_dt, b_dt, nullptr, delta, BT, DI, DR);
    // 7) selective scan (+ fused D-skip and silu gate)
    scan_kernel<<<Bb * (DI / 8), 256, 0, stream>>>(
        delta, xdbl, xp, xr, A_log, Dvec, yb);
    // 8) enc = h0 + y @ w_out            (4096,1024)@(1024,512)
    gemm64<3><<<dim3(DM / 64, BT / 64), 256, 0, stream>>>(
        yb, DI, w_out, nullptr, h0, enc, BT, DM, DI);
    // 9) pooled = mean(enc, axis=-1)
    pool_kernel<<<BT / 4, 256, 0, stream>>>(enc, pooled);
    // 10) out = pooled @ w_cls + b_cls
    cls_kernel<<<(Bb * NC + 255) / 256, 256, 0, stream>>>(pooled, w_cls, b_cls, out);
}

// Round 2
// 484.194 us; speedup vs baseline: 1.6414x; 1.6414x over previous
//
#include <hip/hip_runtime.h>
#include <hip/hip_bf16.h>
#include <cstddef>

#define Bb 8
#define Tt 512
#define NM 128
#define DM 512
#define DI 1024
#define DS 32
#define DR 32
#define DC 4
#define NC 100
#define BT (Bb*Tt)   // 4096

__device__ __forceinline__ float softplus_f(float x) {
    return fmaxf(x, 0.f) + log1pf(expf(-fabsf(x)));
}
__device__ __forceinline__ float silu_fast(float x) {
    return __fdividef(x, 1.f + __expf(-x));
}

// ---------------- generic 64x64 tiled fp32 GEMM: C = epi(A@B) -----------------
// A: (M,K) row-major with row stride lda; B: (K,N) row-major stride N.
// EPI: 0 none, 1 +bias[n], 2 softplus(+bias[n]), 3 +add[m*N+n]
// TSTORE: 0 -> C[m*N+n]; 1 -> C[((m/Tt)*N + n)*Tt + m%Tt]  (per-batch transposed)
template<int EPI, int TSTORE>
__global__ __launch_bounds__(256) void gemm64(
    const float* __restrict__ A, int lda,
    const float* __restrict__ B,
    const float* __restrict__ bias,
    const float* __restrict__ add,
    float* __restrict__ C,
    int M, int N, int K)
{
    __shared__ float As[16][68];   // [k][m]
    __shared__ float Bs[16][64];   // [k][n]
    const int tid = threadIdx.x;
    const int bm = blockIdx.y * 64;
    const int bn = blockIdx.x * 64;
    const int tx = tid & 15;          // n quad
    const int ty = tid >> 4;          // m quad
    const int la_m = tid >> 2;        // 0..63
    const int la_k = (tid & 3) << 2;  // 0,4,8,12
    const int lb_k = tid >> 4;        // 0..15
    const int lb_n = (tid & 15) << 2; // 0..60

    float acc[4][4] = {};
    for (int k0 = 0; k0 < K; k0 += 16) {
        float4 av = *(const float4*)(A + (size_t)(bm + la_m) * lda + k0 + la_k);
        As[la_k + 0][la_m] = av.x;
        As[la_k + 1][la_m] = av.y;
        As[la_k + 2][la_m] = av.z;
        As[la_k + 3][la_m] = av.w;
        const int gn = bn + lb_n;
        const float* bp = B + (size_t)(k0 + lb_k) * N + gn;
        float4 bv;
        if (gn + 3 < N) {
            bv = *(const float4*)bp;
        } else {
            bv.x = (gn + 0 < N) ? bp[0] : 0.f;
            bv.y = (gn + 1 < N) ? bp[1] : 0.f;
            bv.z = (gn + 2 < N) ? bp[2] : 0.f;
            bv.w = (gn + 3 < N) ? bp[3] : 0.f;
        }
        *(float4*)&Bs[lb_k][lb_n] = bv;
        __syncthreads();
        #pragma unroll
        for (int k = 0; k < 16; ++k) {
            float4 a = *(const float4*)&As[k][ty << 2];
            float4 b = *(const float4*)&Bs[k][tx << 2];
            float ar[4] = {a.x, a.y, a.z, a.w};
            float br[4] = {b.x, b.y, b.z, b.w};
            #pragma unroll
            for (int i = 0; i < 4; ++i)
                #pragma unroll
                for (int j = 0; j < 4; ++j)
                    acc[i][j] = fmaf(ar[i], br[j], acc[i][j]);
        }
        __syncthreads();
    }
    if (TSTORE == 0) {
        #pragma unroll
        for (int i = 0; i < 4; ++i) {
            const int gm = bm + (ty << 2) + i;
            #pragma unroll
            for (int j = 0; j < 4; ++j) {
                const int gn = bn + (tx << 2) + j;
                if (gn < N) {
                    float v = acc[i][j];
                    if (EPI == 1) v += bias[gn];
                    else if (EPI == 2) v = softplus_f(v + bias[gn]);
                    else if (EPI == 3) v += add[(size_t)gm * N + gn];
                    C[(size_t)gm * N + gn] = v;
                }
            }
        }
    } else {
        // transposed store: one float4 (4 consecutive t) per j
        const int bq = bm >> 9;              // batch index (Tt = 512)
        const int tt0 = (bm & (Tt - 1)) + (ty << 2);
        #pragma unroll
        for (int j = 0; j < 4; ++j) {
            const int gn = bn + (tx << 2) + j;
            if (gn < N) {
                float4 v;
                float* vv = (float*)&v;
                #pragma unroll
                for (int i = 0; i < 4; ++i) {
                    float t = acc[i][j];
                    if (EPI == 2) t = softplus_f(t + bias[gn]);
                    vv[i] = t;
                }
                *(float4*)(C + ((size_t)bq * N + gn) * Tt + tt0) = v;
            }
        }
    }
}

// --------- GEMM with per-batch-transposed A: A_T layout (b, K, Tt) ------------
// C[m][n] = sum_k A_T[(b*K + k)*Tt + t] * B[k][n],  m = b*Tt + t
// EPI: 0 none, 3 +add[m*N+n]
template<int EPI>
__global__ __launch_bounds__(256) void gemm_at(
    const float* __restrict__ A_T,
    const float* __restrict__ B,
    const float* __restrict__ add,
    float* __restrict__ C,
    int M, int N, int K)
{
    __shared__ float As[16][68];   // [k][m]
    __shared__ float Bs[16][64];   // [k][n]
    const int tid = threadIdx.x;
    const int bm = blockIdx.y * 64;
    const int bn = blockIdx.x * 64;
    const int tx = tid & 15;
    const int ty = tid >> 4;
    const int lb_k = tid >> 4;        // 0..15
    const int lb_n = (tid & 15) << 2; // 0..60
    const int bq = bm >> 9;           // batch
    const int tt0 = bm & (Tt - 1);

    float acc[4][4] = {};
    for (int k0 = 0; k0 < K; k0 += 16) {
        // A tile: rows k, cols t (contiguous) — same pattern as B
        float4 av = *(const float4*)(A_T + ((size_t)bq * K + k0 + lb_k) * Tt + tt0 + lb_n);
        *(float4*)&As[lb_k][lb_n] = av;
        const int gn = bn + lb_n;
        const float* bp = B + (size_t)(k0 + lb_k) * N + gn;
        float4 bv;
        if (gn + 3 < N) {
            bv = *(const float4*)bp;
        } else {
            bv.x = (gn + 0 < N) ? bp[0] : 0.f;
            bv.y = (gn + 1 < N) ? bp[1] : 0.f;
            bv.z = (gn + 2 < N) ? bp[2] : 0.f;
            bv.w = (gn + 3 < N) ? bp[3] : 0.f;
        }
        *(float4*)&Bs[lb_k][lb_n] = bv;
        __syncthreads();
        #pragma unroll
        for (int k = 0; k < 16; ++k) {
            float4 a = *(const float4*)&As[k][ty << 2];
            float4 b = *(const float4*)&Bs[k][tx << 2];
            float ar[4] = {a.x, a.y, a.z, a.w};
            float br[4] = {b.x, b.y, b.z, b.w};
            #pragma unroll
            for (int i = 0; i < 4; ++i)
                #pragma unroll
                for (int j = 0; j < 4; ++j)
                    acc[i][j] = fmaf(ar[i], br[j], acc[i][j]);
        }
        __syncthreads();
    }
    #pragma unroll
    for (int i = 0; i < 4; ++i) {
        const int gm = bm + (ty << 2) + i;
        #pragma unroll
        for (int j = 0; j < 4; ++j) {
            const int gn = bn + (tx << 2) + j;
            if (gn < N) {
                float v = acc[i][j];
                if (EPI == 3) v += add[(size_t)gm * N + gn];
                C[(size_t)gm * N + gn] = v;
            }
        }
    }
}

// ---------------- RMSNorm over DM=512, one block per row ----------------------
__global__ __launch_bounds__(256) void rms_kernel(
    const float* __restrict__ h0, const float* __restrict__ w, float* __restrict__ xn)
{
    const int row = blockIdx.x;
    const float* p = h0 + (size_t)row * DM;
    const int tid = threadIdx.x;
    float v0 = p[tid], v1 = p[tid + 256];
    float ss = v0 * v0 + v1 * v1;
    #pragma unroll
    for (int m = 32; m; m >>= 1) ss += __shfl_xor(ss, m);
    __shared__ float wsum[4];
    if ((tid & 63) == 0) wsum[tid >> 6] = ss;
    __syncthreads();
    const float tot = wsum[0] + wsum[1] + wsum[2] + wsum[3];
    const float scale = rsqrtf(tot * (1.0f / DM) + 1e-5f);
    xn[(size_t)row * DM + tid]       = v0 * scale * w[tid];
    xn[(size_t)row * DM + tid + 256] = v1 * scale * w[tid + 256];
}

// -------- causal depthwise conv (DC=4) + SiLU, outputs TRANSPOSED (b,di,t) ----
// also copies the gate residual xr[:, DI:] transposed (raw, silu applied later)
__global__ __launch_bounds__(256) void conv_tr_kernel(
    const float* __restrict__ xr, const float* __restrict__ cw,
    const float* __restrict__ cb, float* __restrict__ xpT, float* __restrict__ resT)
{
    __shared__ float tp[64][65];  // [t_local][di_local]
    __shared__ float tr[64][65];
    const int di0 = blockIdx.x * 64;
    const int t0  = blockIdx.y * 64;
    const int b   = blockIdx.z;
    const int c  = threadIdx.x & 63;   // di_local (phase1) / t_local (phase2)
    const int r4 = threadIdx.x >> 6;   // 0..3
    const int di = di0 + c;
    const float bias = cb[di];
    float w0 = cw[di * DC + 0], w1 = cw[di * DC + 1],
          w2 = cw[di * DC + 2], w3 = cw[di * DC + 3];
    #pragma unroll
    for (int rr = 0; rr < 64; rr += 4) {
        const int t = t0 + rr + r4;
        const int bt = b * Tt + t;
        float acc = bias;
        if (t >= 3) {
            acc = fmaf(w0, xr[(size_t)(bt - 3) * (2 * DI) + di], acc);
            acc = fmaf(w1, xr[(size_t)(bt - 2) * (2 * DI) + di], acc);
            acc = fmaf(w2, xr[(size_t)(bt - 1) * (2 * DI) + di], acc);
        } else {
            if (t >= 1) acc = fmaf(w2, xr[(size_t)(bt - 1) * (2 * DI) + di], acc);
            if (t >= 2) acc = fmaf(w1, xr[(size_t)(bt - 2) * (2 * DI) + di], acc);
        }
        acc = fmaf(w3, xr[(size_t)bt * (2 * DI) + di], acc);
        tp[rr + r4][c] = silu_fast(acc);
        tr[rr + r4][c] = xr[(size_t)bt * (2 * DI) + DI + di];
    }
    __syncthreads();
    #pragma unroll
    for (int dd = 0; dd < 64; dd += 4) {
        const int dw = dd + r4;
        const size_t o = ((size_t)b * DI + di0 + dw) * Tt + t0 + c;
        xpT[o]  = tp[c][dw];
        resT[o] = tr[c][dw];
    }
}

// ---------------- selective scan (transposed streams) -------------------------
// lane s of 32 per channel (b,di); all per-t streams contiguous in t.
__global__ __launch_bounds__(256) void scan_kernel(
    const float* __restrict__ deltaT, // (B*DI, Tt)
    const float* __restrict__ xdbl,   // (BT, 96): [dt(32) | B(32) | C(32)]
    const float* __restrict__ xpT,    // (B*DI, Tt)  u
    const float* __restrict__ resT,   // (B*DI, Tt)  gate residual
    const float* __restrict__ A_log,  // (DI, DS)
    const float* __restrict__ Dvec,   // (DI)
    float* __restrict__ yT)           // (B*DI, Tt)
{
    const int g = threadIdx.x >> 5;
    const int s = threadIdx.x & 31;
    const int b = blockIdx.x >> 7;
    const int di = ((blockIdx.x & 127) << 3) + g;
    const int ch = b * DI + di;
    const float Ads = -expf(A_log[di * DS + s]);
    const float Dv = Dvec[di];
    const float* dp = deltaT + (size_t)ch * Tt;
    const float* up = xpT + (size_t)ch * Tt;
    const float* rp = resT + (size_t)ch * Tt;
    const float* xd = xdbl + (size_t)b * Tt * 96;
    float* yp = yT + (size_t)ch * Tt;
    float h = 0.f;
    for (int t0 = 0; t0 < Tt; t0 += 32) {
        float yreg = 0.f;
        #pragma unroll
        for (int tq = 0; tq < 8; ++tq) {
            const int tb = t0 + tq * 4;
            float4 d4 = *(const float4*)(dp + tb);
            float4 u4 = *(const float4*)(up + tb);
            float dv[4] = {d4.x, d4.y, d4.z, d4.w};
            float uv[4] = {u4.x, u4.y, u4.z, u4.w};
            #pragma unroll
            for (int q = 0; q < 4; ++q) {
                const int tloc = tq * 4 + q;
                const float dt = dv[q];
                const float u  = uv[q];
                const float Btv = xd[(tb + q) * 96 + DR + s];
                const float Ctv = xd[(tb + q) * 96 + DR + DS + s];
                const float dA = __expf(dt * Ads);
                h = fmaf(dA, h, dt * u * Btv);
                float ps = h * Ctv;
                ps += __shfl_xor(ps, 16);
                ps += __shfl_xor(ps, 8);
                ps += __shfl_xor(ps, 4);
                ps += __shfl_xor(ps, 2);
                ps += __shfl_xor(ps, 1);
                const float yv = fmaf(u, Dv, ps);
                if (tloc == s) yreg = yv;
            }
        }
        // gate applied once per 32 steps, coalesced 128B load + store per group
        yp[t0 + s] = yreg * silu_fast(rp[t0 + s]);
    }
}

// ---------------- mean-pool over DM, one wave per row -------------------------
__global__ __launch_bounds__(256) void pool_kernel(
    const float* __restrict__ enc, float* __restrict__ pooled)
{
    const int row = blockIdx.x * 4 + (threadIdx.x >> 6);
    const int lane = threadIdx.x & 63;
    const float* p = enc + (size_t)row * DM;
    float sacc = 0.f;
    #pragma unroll
    for (int i = 0; i < DM / 64; ++i) sacc += p[lane + 64 * i];
    #pragma unroll
    for (int m = 32; m; m >>= 1) sacc += __shfl_xor(sacc, m);
    if (lane == 0) pooled[row] = sacc * (1.0f / DM);
}

// ---------------- classifier ---------------------------------------------------
__global__ __launch_bounds__(256) void cls_kernel(
    const float* __restrict__ pooled, const float* __restrict__ w_cls,
    const float* __restrict__ b_cls, float* __restrict__ out)
{
    const int idx = blockIdx.x * 256 + threadIdx.x;
    if (idx >= Bb * NC) return;
    const int b = idx / NC, c = idx % NC;
    float acc = b_cls[c];
    for (int t = 0; t < DM; ++t)
        acc = fmaf(pooled[b * DM + t], w_cls[t * NC + c], acc);
    out[idx] = acc;
}

extern "C" void kernel_launch(void* const* d_in, const int* in_sizes, int n_in,
                              void* d_out, int out_size, void* d_ws, size_t ws_size,
                              hipStream_t stream) {
    const float* x      = (const float*)d_in[0];
    const float* w_proj = (const float*)d_in[1];
    const float* b_proj = (const float*)d_in[2];
    const float* rms_w  = (const float*)d_in[3];
    const float* w_in   = (const float*)d_in[4];
    const float* conv_w = (const float*)d_in[5];
    const float* conv_b = (const float*)d_in[6];
    const float* w_xprj = (const float*)d_in[7];
    const float* w_dt   = (const float*)d_in[8];
    const float* b_dt   = (const float*)d_in[9];
    const float* A_log  = (const float*)d_in[10];
    const float* Dvec   = (const float*)d_in[11];
    const float* w_out  = (const float*)d_in[12];
    const float* w_cls  = (const float*)d_in[13];
    const float* b_cls  = (const float*)d_in[14];
    float* out = (float*)d_out;

    float* ws = (float*)d_ws;
    float* h0     = ws;                            // 2,097,152
    float* xn     = h0 + (size_t)BT * DM;          // 2,097,152
    float* xr     = xn + (size_t)BT * DM;          // 8,388,608
    float* xpT    = xr + (size_t)BT * 2 * DI;      // 4,194,304
    float* resT   = xpT + (size_t)Bb * DI * Tt;    // 4,194,304
    float* xdbl   = resT + (size_t)Bb * DI * Tt;   // 393,216
    float* pooled = xdbl + (size_t)BT * 96;        // 4,096
    float* deltaT = xr;                            // alias: xr dead after conv_tr
    float* yT     = xr + (size_t)Bb * DI * Tt;     // alias: upper half of xr
    float* enc    = xn;                            // alias: xn dead after gemm3

    // 1) h0 = x @ w_proj + b_proj
    gemm64<1,0><<<dim3(DM / 64, BT / 64), 256, 0, stream>>>(
        x, NM, w_proj, b_proj, nullptr, h0, BT, DM, NM);
    // 2) xn = rmsnorm(h0) * rms_w
    rms_kernel<<<BT, 256, 0, stream>>>(h0, rms_w, xn);
    // 3) xr = xn @ w_in
    gemm64<0,0><<<dim3(2 * DI / 64, BT / 64), 256, 0, stream>>>(
        xn, DM, w_in, nullptr, nullptr, xr, BT, 2 * DI, DM);
    // 4) xpT = silu(causal_dwconv(xr[:, :DI]))^T ; resT = xr[:, DI:]^T
    conv_tr_kernel<<<dim3(DI / 64, Tt / 64, Bb), 256, 0, stream>>>(
        xr, conv_w, conv_b, xpT, resT);
    // 5) xdbl = xp @ w_xproj   (A read transposed)
    gemm_at<0><<<dim3((96 + 63) / 64, BT / 64), 256, 0, stream>>>(
        xpT, w_xprj, nullptr, xdbl, BT, 96, DI);
    // 6) deltaT = softplus(dt @ w_dt + b_dt)^T
    gemm64<2,1><<<dim3(DI / 64, BT / 64), 256, 0, stream>>>(
        xdbl, 96, w_dt, b_dt, nullptr, deltaT, BT, DI, DR);
    // 7) selective scan (+ fused D-skip and silu gate), writes yT
    scan_kernel<<<Bb * (DI / 8), 256, 0, stream>>>(
        deltaT, xdbl, xpT, resT, A_log, Dvec, yT);
    // 8) enc = h0 + y @ w_out  (A read transposed)
    gemm_at<3><<<dim3(DM / 64, BT / 64), 256, 0, stream>>>(
        yT, w_out, h0, enc, BT, DM, DI);
    // 9) pooled = mean(enc, axis=-1)
    pool_kernel<<<BT / 4, 256, 0, stream>>>(enc, pooled);
    // 10) out = pooled @ w_cls + b_cls
    cls_kernel<<<(Bb * NC + 255) / 256, 256, 0, stream>>>(pooled, w_cls, b_cls, out);
}